// Round 10
// baseline (38.950 us; speedup 1.0000x reference)
//
#include <hip/hip_runtime.h>

#define FRAME 160
#define ORDER 16
#define LPC_EPS 1e-8f
#define NF 16        // frames per block (halved: occupancy experiment)
#define BS 128       // threads per block (2 waves); 8 threads per frame
#define SEG 20       // samples per part (8 parts per frame)
#define SX 164       // padded LDS row stride in floats (+4-float skew vs 160)
#define AB 20        // rbuf/abuf row stride in floats
#define QPB (NF * FRAME / 4 / BS)  // 5 float4 iterations per thread stage-in/out

// Native clang vector for nontemporal builtin (HIP_vector_type is a class ->
// rejected by __builtin_nontemporal_store; ext_vector_type lowers to the same
// global_store_dwordx4 with the nt policy bit).
typedef float f4nt __attribute__((ext_vector_type(4)));

// Round 10 = r9 (38.56us best: r1 skeleton + nt stage-out) with HALVED block:
// NF=16/BS=128, LDS 13,056B -> 12 blocks/CU LDS-wise (was 6), 8000 blocks.
// Why: r9 counters show NO pipe >60% duty (HBM 55%, VALU 43%, LDS 45%) --
// latency-bound, not throughput-bound -- while OccupancyPercent sits at ~36%
// (~12 waves/CU = ~3 blocks) in EVERY variant r0-r9 despite LDS/VGPR allowing
// 24 waves. Smaller blocks = more independent phase-pipelines per CU: block
// i's store phase overlaps block j's load/compute via natural inter-block
// staggering (safe per r4 -- unlike intra-block free-running, which
// de-clustered traffic). Ledger-kept: lock-step barriers (r4), coalesced
// stores (r2), centralized Levinson (r6), LDS staging not DMA (r7), nt out
// (r9). Pre-committed: if occupancy ~36% and dur ~38-40 again, residency is
// capped by an invariant -> structural floor, declare ROOFLINE next round.
__global__ __launch_bounds__(BS, 4) void lpc_fused(const float* __restrict__ x,
                                                   float* __restrict__ out) {
    __shared__ float xs[NF * SX];    // 10,496 B
    __shared__ float rbuf[NF * AB];  //  1,280 B
    __shared__ float abuf[NF * AB];  //  1,280 B

    const int t = threadIdx.x;
    const long long base = (long long)blockIdx.x * (NF * FRAME);

    // ---- stage in: 640 consecutive float4, fully coalesced ----
#pragma unroll
    for (int it = 0; it < QPB; ++it) {
        int p = it * BS + t;              // quad index within block [0,640)
        int f = p / 40;                   // 40 quads per frame
        int off = (p - f * 40) * 4;
        float4 v = *(const float4*)(x + base + 4 * p);
        *(float4*)(&xs[f * SX + off]) = v;
    }
    __syncthreads();

    const int fi = t >> 3;       // frame within block [0,16)
    const int part = t & 7;      // n-range: [20*part, 20*part+20)
    const int sbase = SEG * part;

    // ---- window w[j] = x[sbase + j], j in [0,36), zero-padded past frame end ----
    float w[SEG + ORDER];
#pragma unroll
    for (int m = 0; m < (SEG + ORDER) / 4; ++m) {
        int idx = sbase + 4 * m;
        float4 v = make_float4(0.f, 0.f, 0.f, 0.f);
        if (idx < FRAME) v = *(const float4*)(&xs[fi * SX + idx]);
        w[4 * m + 0] = v.x; w[4 * m + 1] = v.y;
        w[4 * m + 2] = v.z; w[4 * m + 3] = v.w;
    }

    // ---- FIR look-back: pre[j] = x[sbase - 16 + j], zeros before frame start ----
    float pre[ORDER];
#pragma unroll
    for (int m = 0; m < ORDER / 4; ++m) {
        int idx = sbase - ORDER + 4 * m;
        float4 v = make_float4(0.f, 0.f, 0.f, 0.f);
        if (idx >= 0) v = *(const float4*)(&xs[fi * SX + idx]);
        pre[4 * m + 0] = v.x; pre[4 * m + 1] = v.y;
        pre[4 * m + 2] = v.z; pre[4 * m + 3] = v.w;
    }

    // ---- partial autocorrelation over 20 samples, all 17 lags ----
    float r[ORDER + 1];
#pragma unroll
    for (int k = 0; k <= ORDER; ++k) r[k] = 0.f;
#pragma unroll
    for (int n = 0; n < SEG; ++n) {
#pragma unroll
        for (int k = 0; k <= ORDER; ++k) {
            r[k] = fmaf(w[n], w[n + k], r[k]);
        }
    }
    // 8-lane butterfly: every lane of the group gets full-frame r[k]
#pragma unroll
    for (int k = 0; k <= ORDER; ++k) {
        r[k] += __shfl_xor(r[k], 1);
        r[k] += __shfl_xor(r[k], 2);
        r[k] += __shfl_xor(r[k], 4);
    }

    // ---- publish r[] once per frame (lane part==0) ----
    if (part == 0) {
#pragma unroll
        for (int m = 0; m < 4; ++m)
            *(float4*)(&rbuf[fi * AB + 4 * m]) =
                make_float4(r[4 * m], r[4 * m + 1], r[4 * m + 2], r[4 * m + 3]);
        rbuf[fi * AB + 16] = r[16];
    }
    __syncthreads();

    // ---- Levinson-Durbin: one thread per frame (16 lanes of wave 0) ----
    if (t < NF) {
        float rr[ORDER + 1];
#pragma unroll
        for (int m = 0; m < 4; ++m) {
            float4 v = *(const float4*)(&rbuf[t * AB + 4 * m]);
            rr[4 * m + 0] = v.x; rr[4 * m + 1] = v.y;
            rr[4 * m + 2] = v.z; rr[4 * m + 3] = v.w;
        }
        rr[16] = rbuf[t * AB + 16];

        float a[ORDER + 1];
        a[0] = 1.f;
#pragma unroll
        for (int j = 1; j <= ORDER; ++j) a[j] = 0.f;
        float e = (rr[0] != 0.f) ? rr[0] : LPC_EPS;  // e >= EPS > 0 afterwards
#pragma unroll
        for (int i = 1; i <= ORDER; ++i) {
            float acc = rr[i];
#pragma unroll
            for (int j = 1; j < i; ++j) acc -= a[j] * rr[i - j];
            // e >= EPS always; v_rcp_f32 (~1 ulp) vs IEEE divide: rel err ~1e-7
            float k = acc * __builtin_amdgcn_rcpf(e);
            // a_new[j] = a[j] - k*a[i-j] for j=1..i-1, done as (j, i-j) pairs:
#pragma unroll
            for (int j = 1; 2 * j < i; ++j) {
                float aj = a[j], aij = a[i - j];
                a[j]     = aj  - k * aij;
                a[i - j] = aij - k * aj;
            }
            if ((i & 1) == 0) {
                int m = i >> 1;                 // self-paired middle element
                a[m] = a[m] - k * a[m];
            }
            a[i] = k;
            e = fmaxf(e * (1.f - k * k), LPC_EPS);
        }
        // publish a[1..16] (a[0]==1 implicit)
#pragma unroll
        for (int m = 0; m < 4; ++m)
            *(float4*)(&abuf[t * AB + 4 * m]) =
                make_float4(a[4 * m + 1], a[4 * m + 2], a[4 * m + 3], a[4 * m + 4]);
    }
    __syncthreads();  // abuf visible; all xs reads already done before rbuf sync

    // ---- read back a[] (same address across the 8 lanes -> LDS broadcast) ----
    float a[ORDER + 1];
    a[0] = 1.f;
#pragma unroll
    for (int m = 0; m < 4; ++m) {
        float4 v = *(const float4*)(&abuf[fi * AB + 4 * m]);
        a[4 * m + 1] = v.x; a[4 * m + 2] = v.y;
        a[4 * m + 3] = v.z; a[4 * m + 4] = v.w;
    }

    // ---- FIR: res[sbase+n] = sum_k a[k] * x[sbase+n-k], written in place ----
#pragma unroll
    for (int m = 0; m < SEG / 4; ++m) {
        float o[4];
#pragma unroll
        for (int i = 0; i < 4; ++i) {
            int n = 4 * m + i;
            float s = 0.f;
#pragma unroll
            for (int k = 0; k <= ORDER; ++k) {
                int j = n - k;                       // compile-time
                float xv = (j >= 0) ? w[j] : pre[ORDER + j];
                s = fmaf(a[k], xv, s);
            }
            o[i] = s;
        }
        *(float4*)(&xs[fi * SX + sbase + 4 * m]) = make_float4(o[0], o[1], o[2], o[3]);
    }
    __syncthreads();

    // ---- stage out: fully coalesced, non-temporal (r9 win: -1.2us) ----
#pragma unroll
    for (int it = 0; it < QPB; ++it) {
        int p = it * BS + t;
        int f = p / 40;
        int off = (p - f * 40) * 4;
        f4nt v = *(const f4nt*)(&xs[f * SX + off]);
        __builtin_nontemporal_store(v, (f4nt*)(out + base + 4 * p));
    }
}

extern "C" void kernel_launch(void* const* d_in, const int* in_sizes, int n_in,
                              void* d_out, int out_size, void* d_ws, size_t ws_size,
                              hipStream_t stream) {
    const float* x = (const float*)d_in[0];
    float* out = (float*)d_out;
    int total = in_sizes[0];                 // 20,480,000 = 128,000 frames
    int n_frames = total / FRAME;
    int n_blocks = n_frames / NF;            // 8000 (exact for this problem shape)
    lpc_fused<<<n_blocks, BS, 0, stream>>>(x, out);
}